// Round 7
// baseline (8737.765 us; speedup 1.0000x reference)
//
#include <hip/hip_runtime.h>
#include <math.h>

#define NNEUR 300          // NN
#define NFEAT 20           // NF
#define NPAD  320          // padded n-dimension
#define MAUGP 336          // 300 r + 20 image + 1 hold + 1 const + 14 pad = 16*21
#define NOUT  50
#define NPMAC 100          // NPM
#define TSTEPS 500
#define BATCH 1024
#define NWAVE 16
#define MCHUNK 21          // m-rows per wave
#define RROWS 17           // rows 0..16: register-resident (R) or streamed (S)
#define LROWS 4            // rows 17..20: LDS-resident (both kernels)

// Augmented transposed weight matrix W[m][n], n padded to 320:
//   m in [0,300):   W[m][n] = J[n][m]
//   m in [300,320): W[m][n] = I[n][m-300]
//   m == 320:       W[m][n] = S[n]
//   m == 321:       W[m][n] = Bb[n]   (activation fixed at 1)
//   else / n>=300:  0
__global__ void build_w_kernel(const float* __restrict__ J,
                               const float* __restrict__ I,
                               const float* __restrict__ S,
                               const float* __restrict__ Bb,
                               float* __restrict__ W) {
    int e = blockIdx.x * 256 + threadIdx.x;
    if (e >= MAUGP * NPAD) return;
    int m = e / NPAD, n = e % NPAD;
    float v = 0.0f;
    if (n < NNEUR) {
        if (m < NNEUR)                   v = J[n * NNEUR + m];
        else if (m < NNEUR + NFEAT)      v = I[n * NFEAT + (m - NNEUR)];
        else if (m == NNEUR + NFEAT)     v = S[n];
        else if (m == NNEUR + NFEAT + 1) v = Bb[n];
    }
    W[e] = v;
}

// ---------------- shared pieces (identical in both kernels) ----------------
// LDS layouts chosen for bank-conflict-freedom:
//   part[w][n][b]: Phase C reads/writes at word 4n+b are lane-consecutive;
//                  Phase B per-lane writes are 64B-contiguous float4s.
//   xs[n][b]: same Phase C mapping.
#define DECLARE_LDS \
    __shared__ __align__(16) float Wl[NWAVE][LROWS][NPAD]; \
    __shared__ __align__(16) float part[8][NPAD][4]; \
    __shared__ __align__(16) float raug[MAUGP][4]; \
    __shared__ __align__(16) float xs[NPAD][4]; \
    __shared__ float fcwt[NPMAC][NOUT]; \
    __shared__ float fcbs[NOUT];

#define COMMON_IDS \
    const int tid = threadIdx.x; \
    const int wid = tid >> 6; \
    const int l   = tid & 63; \
    const int b0  = blockIdx.x * 4; \
    const int m0  = wid * MCHUNK;

#define INIT_STATE \
    for (int i = tid; i < MAUGP * 4; i += 1024) ((float*)raug)[i] = 0.0f; \
    for (int i = tid; i < NPMAC * NOUT; i += 1024) { \
        int p = i / NOUT, o = i - (i / NOUT) * NOUT; \
        fcwt[p][o] = fcw[o * NPMAC + p]; \
    } \
    if (tid < NOUT) fcbs[tid] = fcb[tid]; \
    __syncthreads(); \
    for (int i = tid; i < NNEUR; i += 1024) { \
        float xv = x0[i]; \
        float rv = fmaxf(tanhf(xv), 0.0f); \
        _Pragma("unroll") \
        for (int b = 0; b < 4; ++b) { xs[i][b] = xv; raug[i][b] = rv; } \
    } \
    if (tid < 4) raug[NNEUR + NFEAT + 1][tid] = 1.0f;

#define LOAD_WL \
    _Pragma("unroll") \
    for (int i = 0; i < LROWS; ++i) { \
        *reinterpret_cast<float4*>(&Wl[wid][i][4 * l]) = \
            *reinterpret_cast<const float4*>(&W[(size_t)(m0 + RROWS + i) * NPAD + 4 * l]); \
        Wl[wid][i][256 + l] = W[(size_t)(m0 + RROWS + i) * NPAD + 256 + l]; \
    }

#define DATA_PROLOGUE \
    float4 dstage = make_float4(0.f, 0.f, 0.f, 0.f); \
    if (tid < NFEAT + 1) { \
        float4 d0 = *reinterpret_cast<const float4*>(data + (size_t)tid * BATCH + b0); \
        *reinterpret_cast<float4*>(&raug[NNEUR + tid][0]) = d0; \
        dstage = *reinterpret_cast<const float4*>( \
            data + ((size_t)(NFEAT + 1) + tid) * BATCH + b0); \
    } \
    __syncthreads();

#define DECL_ACC \
    float a00=0.f,a01=0.f,a02=0.f,a03=0.f, a10=0.f,a11=0.f,a12=0.f,a13=0.f, \
          a20=0.f,a21=0.f,a22=0.f,a23=0.f, a30=0.f,a31=0.f,a32=0.f,a33=0.f, \
          t0=0.f,t1=0.f,t2=0.f,t3=0.f;

#define FMA_ROW_SC(WX, WY, WZ, WW, WV, RIDX) { \
        const float4 rv_ = *reinterpret_cast<const float4*>(&raug[(RIDX)][0]); \
        a00 += (WX)*rv_.x; a01 += (WX)*rv_.y; a02 += (WX)*rv_.z; a03 += (WX)*rv_.w; \
        a10 += (WY)*rv_.x; a11 += (WY)*rv_.y; a12 += (WY)*rv_.z; a13 += (WY)*rv_.w; \
        a20 += (WZ)*rv_.x; a21 += (WZ)*rv_.y; a22 += (WZ)*rv_.z; a23 += (WZ)*rv_.w; \
        a30 += (WW)*rv_.x; a31 += (WW)*rv_.y; a32 += (WW)*rv_.z; a33 += (WW)*rv_.w; \
        t0  += (WV)*rv_.x; t1  += (WV)*rv_.y; t2  += (WV)*rv_.z; t3  += (WV)*rv_.w; }

#define FMA_LDS_ROWS \
    _Pragma("unroll") \
    for (int i = 0; i < LROWS; ++i) { \
        const float4 wv_ = *reinterpret_cast<const float4*>(&Wl[wid][i][4 * l]); \
        const float wlt_ = Wl[wid][i][256 + l]; \
        FMA_ROW_SC(wv_.x, wv_.y, wv_.z, wv_.w, wlt_, m0 + RROWS + i) \
    }

#define PART_STAGE1 \
    if (wid < 8) { \
        *reinterpret_cast<float4*>(&part[wid][4*l+0][0]) = make_float4(a00,a01,a02,a03); \
        *reinterpret_cast<float4*>(&part[wid][4*l+1][0]) = make_float4(a10,a11,a12,a13); \
        *reinterpret_cast<float4*>(&part[wid][4*l+2][0]) = make_float4(a20,a21,a22,a23); \
        *reinterpret_cast<float4*>(&part[wid][4*l+3][0]) = make_float4(a30,a31,a32,a33); \
        *reinterpret_cast<float4*>(&part[wid][256+l][0]) = make_float4(t0,t1,t2,t3); \
    }

#define PART_RMW(PTR, VX, VY, VZ, VW) { \
        float4 p4_ = *reinterpret_cast<float4*>(PTR); \
        p4_.x += (VX); p4_.y += (VY); p4_.z += (VZ); p4_.w += (VW); \
        *reinterpret_cast<float4*>(PTR) = p4_; }

#define PART_STAGE2 \
    if (wid >= 8) { \
        const int w8 = wid - 8; \
        PART_RMW(&part[w8][4*l+0][0], a00, a01, a02, a03) \
        PART_RMW(&part[w8][4*l+1][0], a10, a11, a12, a13) \
        PART_RMW(&part[w8][4*l+2][0], a20, a21, a22, a23) \
        PART_RMW(&part[w8][4*l+3][0], a30, a31, a32, a33) \
        PART_RMW(&part[w8][256+l][0], t0, t1, t2, t3) \
    }

// Phase C (reduce 8 partials, state update) + commit data[t+1] + prefetch
// data[t+2]. Lane-consecutive LDS addresses throughout.
#define PHASE_C_AND_COMMIT \
    { \
        int bb = tid & 3, nn = tid >> 2; \
        float s_ = part[0][nn][bb] + part[1][nn][bb] + part[2][nn][bb] + part[3][nn][bb] \
                 + part[4][nn][bb] + part[5][nn][bb] + part[6][nn][bb] + part[7][nn][bb]; \
        float xo_  = xs[nn][bb]; \
        float pre_ = xo_ + (s_ - xo_) * 0.1f; \
        xs[nn][bb] = pre_; \
        raug[nn][bb] = fmaxf(tanhf(pre_), 0.0f); \
        if (tid < 256) { \
            int n2 = 256 + (tid >> 2); \
            if (n2 < NNEUR) { \
                float s2 = part[0][n2][bb] + part[1][n2][bb] + part[2][n2][bb] + part[3][n2][bb] \
                         + part[4][n2][bb] + part[5][n2][bb] + part[6][n2][bb] + part[7][n2][bb]; \
                float xo2  = xs[n2][bb]; \
                float pre2 = xo2 + (s2 - xo2) * 0.1f; \
                xs[n2][bb] = pre2; \
                raug[n2][bb] = fmaxf(tanhf(pre2), 0.0f); \
            } \
        } \
        if (tid < NFEAT + 1 && t + 1 < TSTEPS) { \
            *reinterpret_cast<float4*>(&raug[NNEUR + tid][0]) = dstage; \
            if (t + 2 < TSTEPS) \
                dstage = *reinterpret_cast<const float4*>( \
                    data + ((size_t)(t + 2) * (NFEAT + 1) + tid) * BATCH + b0); \
        } \
    }

#define PHASE_D \
    if (tid < 800) { \
        int pair = tid >> 2, seg = tid & 3; \
        int b_ = pair / NOUT, o_ = pair - (pair / NOUT) * NOUT; \
        int pb_ = seg * 25; \
        float y_ = 0.0f; \
        _Pragma("unroll 5") \
        for (int k = 0; k < 25; ++k) \
            y_ += raug[pb_ + k][b_] * fcwt[pb_ + k][o_]; \
        y_ += __shfl_down(y_, 1, 4); \
        y_ += __shfl_down(y_, 2, 4); \
        if (seg == 0) \
            out[((size_t)t * BATCH + b0 + b_) * NOUT + o_] = y_ + fcbs[o_]; \
    }

#define ROWS_ITER(F) F(0) F(1) F(2) F(3) F(4) F(5) F(6) F(7) F(8) \
                     F(9) F(10) F(11) F(12) F(13) F(14) F(15) F(16)

// ------------------- Kernel R: register-resident weights -------------------
// __launch_bounds__(1024, 1): hypothesis — the 64-VGPR clamp in rounds 2-6
// tracked the REQUESTED min_waves_per_EU (=4); min=1 lifts the cap to the
// wg-1024 schedulability limit (128). Demand ~120 self-limits below it.
// kernel_launch gates on (numRegs >= 96 && localSizeBytes == 0).
__global__ __launch_bounds__(1024, 1) void rnn_kernel_reg(
    const float* __restrict__ W, const float* __restrict__ data,
    const float* __restrict__ x0, const float* __restrict__ fcw,
    const float* __restrict__ fcb, float* __restrict__ out)
{
    DECLARE_LDS
    COMMON_IDS
    INIT_STATE

#define WDECL(i) float wx##i, wy##i, wz##i, ww##i, wv##i;
    ROWS_ITER(WDECL)
#define WLOAD(i) { \
        const float4 t4_ = *reinterpret_cast<const float4*>( \
            &W[(size_t)(m0 + (i)) * NPAD + 4 * l]); \
        wx##i = t4_.x; wy##i = t4_.y; wz##i = t4_.z; ww##i = t4_.w; \
        wv##i = W[(size_t)(m0 + (i)) * NPAD + 256 + l]; }
    ROWS_ITER(WLOAD)
#define WPIN(i) asm volatile("" : "+v"(wx##i), "+v"(wy##i), "+v"(wz##i), \
                                  "+v"(ww##i), "+v"(wv##i));
    ROWS_ITER(WPIN)

    LOAD_WL
    DATA_PROLOGUE

    for (int t = 0; t < TSTEPS; ++t) {
        DECL_ACC
#define WFMA(i) FMA_ROW_SC(wx##i, wy##i, wz##i, ww##i, wv##i, m0 + (i))
        ROWS_ITER(WFMA)
        FMA_LDS_ROWS
        PART_STAGE1
        __syncthreads();
        PART_STAGE2
        __syncthreads();
        PHASE_C_AND_COMMIT
        __syncthreads();
        PHASE_D
        // no barrier needed: D only reads raug rows <100; next iteration's
        // first write to shared state (PART_STAGE1) is after a barrier.
    }
}

// ------------------- Kernel S: depth-5 streamed weights --------------------
// Fallback guaranteed to fit the 64-VGPR budget: 17 rows streamed from L2
// with a 5-deep named-buffer rotation (round 6 was depth-1 => serial latency
// chain); 4 rows in LDS. Demand ~55 regs.
__global__ __launch_bounds__(1024, 4) void rnn_kernel_str(
    const float* __restrict__ W, const float* __restrict__ data,
    const float* __restrict__ x0, const float* __restrict__ fcw,
    const float* __restrict__ fcb, float* __restrict__ out)
{
    DECLARE_LDS
    COMMON_IDS
    INIT_STATE
    LOAD_WL
    const float* Wstream = W + (size_t)m0 * NPAD;   // rows 0..16 of this wave
    DATA_PROLOGUE

    for (int t = 0; t < TSTEPS; ++t) {
        DECL_ACC
        float4 q40, q41, q42, q43, q44;
        float  qt0, qt1, qt2, qt3, qt4;
#define SLOAD(SET, K) { \
        const float* p_ = Wstream + (size_t)(K) * NPAD; \
        q4##SET = *reinterpret_cast<const float4*>(p_ + 4 * l); \
        qt##SET = p_[256 + l]; }
        SLOAD(0, 0) SLOAD(1, 1) SLOAD(2, 2) SLOAD(3, 3) SLOAD(4, 4)
        FMA_LDS_ROWS            // LDS rows fill the latency of loads 0..4
#define SSTEP(K, SET) { \
        FMA_ROW_SC(q4##SET.x, q4##SET.y, q4##SET.z, q4##SET.w, qt##SET, m0 + (K)) \
        if ((K) + 5 < RROWS) SLOAD(SET, (K) + 5) }
        SSTEP(0, 0)  SSTEP(1, 1)  SSTEP(2, 2)  SSTEP(3, 3)  SSTEP(4, 4)
        SSTEP(5, 0)  SSTEP(6, 1)  SSTEP(7, 2)  SSTEP(8, 3)  SSTEP(9, 4)
        SSTEP(10, 0) SSTEP(11, 1) SSTEP(12, 2) SSTEP(13, 3) SSTEP(14, 4)
        SSTEP(15, 0) SSTEP(16, 1)
        PART_STAGE1
        __syncthreads();
        PART_STAGE2
        __syncthreads();
        PHASE_C_AND_COMMIT
        __syncthreads();
        PHASE_D
    }
}

extern "C" void kernel_launch(void* const* d_in, const int* in_sizes, int n_in,
                              void* d_out, int out_size, void* d_ws, size_t ws_size,
                              hipStream_t stream) {
    const float* data = (const float*)d_in[0];
    const float* J    = (const float*)d_in[1];
    const float* I    = (const float*)d_in[2];
    const float* S    = (const float*)d_in[3];
    const float* Bb   = (const float*)d_in[4];
    const float* x0   = (const float*)d_in[5];
    const float* fcw  = (const float*)d_in[6];
    const float* fcb  = (const float*)d_in[7];
    float* out = (float*)d_out;
    float* W   = (float*)d_ws;   // MAUGP*NPAD*4 = 430,080 bytes

    int wtot = MAUGP * NPAD;
    build_w_kernel<<<(wtot + 255) / 256, 256, 0, stream>>>(J, I, S, Bb, W);

    // Deterministic gate: use the register-resident kernel only if it
    // compiled spill-free with the weights actually in registers.
    hipFuncAttributes attr{};
    hipError_t err = hipFuncGetAttributes(&attr, (const void*)rnn_kernel_reg);
    bool useR = (err == hipSuccess) && attr.numRegs >= 96 && attr.localSizeBytes == 0;

    if (useR)
        rnn_kernel_reg<<<256, 1024, 0, stream>>>(W, data, x0, fcw, fcb, out);
    else
        rnn_kernel_str<<<256, 1024, 0, stream>>>(W, data, x0, fcw, fcb, out);
}